// Round 4
// baseline (8276.448 us; speedup 1.0000x reference)
//
#include <hip/hip_runtime.h>
#include <stdint.h>

// Problem constants (from reference)
#define S_WORDS 2048
#define LMAX    16
#define CE      256
#define WE      512
#define HDIM    1024
#define GC      1024   // 4*CE
#define GW      4096   // 4*HDIM
#define KW      768    // WE + CE
#define NWG_RNN 128    // recurrence WGs: 8 units each, 1 unit per wave
#define NWB_WIN 512    // fused wordin producer blocks (2 per 8-row group)
#define NMIR    4      // ring mirrors (fan-in reduction 128 -> 32 pollers/line)
#define RING_U64 (3 * HDIM)   // u64 per mirror (3 slots x 1024)

// Workspace layout (bytes) — high-water 50,331,648 (48 MiB)
#define IN_GATES_OFF 0                       // 2048*4096 fp32 = 33554432
#define LAST_OFF     33554432                // 2048*256 fp32  =  2097152
#define WT2C_OFF     35651584                // 256*1024 float2 = 2097152 (char weights)
#define WT2W_OFF     37748736                // 384*4096 float2 = 12582912
// Ring mirrors + row-ready flags alias WT2c (dead after char_lstm; memset after):
#define RING_OFF     WT2C_OFF                // 4 mirrors * 3 slots * 1024 u64 = 98304
#define FLAGS_OFF    (RING_OFF + NMIR * RING_U64 * 8)  // 256 u32 = 1024

typedef float f32x4 __attribute__((ext_vector_type(4)));

#define LD_AGENT(p) __hip_atomic_load((p), __ATOMIC_RELAXED, __HIP_MEMORY_SCOPE_AGENT)

static __device__ __forceinline__ float sigm(float x) { return 1.0f / (1.0f + __expf(-x)); }
static __device__ __forceinline__ float tanh_fast(float x) {
    float ax = fminf(fabsf(x), 15.0f);
    float e  = __expf(2.0f * ax);
    float t  = (e - 1.0f) / (e + 1.0f);
    return copysignf(t, x);
}

// ---------- prep: transposed k-major float2 pairs for coalesced reads ----------
__global__ void prep_c_kernel(const float* __restrict__ Wih,
                              const float* __restrict__ Whh,
                              float2* __restrict__ WT2c) {
    int idx = blockIdx.x * blockDim.x + threadIdx.x;   // 256*1024
    if (idx >= 256 * GC) return;
    int kp = idx >> 10, row = idx & (GC - 1);
    int k = kp * 2;
    float2 v;
    if (k < CE) { v.x = Wih[row * CE + k];      v.y = Wih[row * CE + k + 1]; }
    else        { v.x = Whh[row * CE + k - CE]; v.y = Whh[row * CE + k - CE + 1]; }
    WT2c[idx] = v;
}

__global__ void prep_w_kernel(const float* __restrict__ Wih,
                              float2* __restrict__ WT2w) {
    int idx = blockIdx.x * blockDim.x + threadIdx.x;   // 384*4096
    if (idx >= 384 * GW) return;
    int kp = idx >> 12, row = idx & (GW - 1);
    float2 v;
    v.x = Wih[row * KW + 2 * kp];
    v.y = Wih[row * KW + 2 * kp + 1];
    WT2w[idx] = v;
}

// ---------- char LSTM: 256 blocks x 256 threads; block handles 8 words ----------
__global__ void __launch_bounds__(256) char_lstm_kernel(
    const int* __restrict__ char_idxs,
    const int* __restrict__ char_lens,
    const float* __restrict__ char_emb,
    const float* __restrict__ bih,
    const float* __restrict__ bhh,
    const float2* __restrict__ WT2c,
    float* __restrict__ last_out)
{
    __shared__ float xh[8][2 * CE];
    const int j = threadIdx.x;
    const int wbase = blockIdx.x * 8;

    float bias[4];
    #pragma unroll
    for (int g = 0; g < 4; g++) bias[g] = bih[g * CE + j] + bhh[g * CE + j];

    int len[8];
    float c[8];
    #pragma unroll
    for (int w = 0; w < 8; w++) {
        c[w] = 0.0f;
        xh[w][CE + j] = 0.0f;
        len[w] = char_lens[wbase + w];
    }

    for (int t = 0; t < LMAX; t++) {
        #pragma unroll
        for (int w = 0; w < 8; w++) {
            int ci = char_idxs[(wbase + w) * LMAX + t];
            xh[w][j] = char_emb[ci * CE + j];
        }
        __syncthreads();

        float acc[4][8];
        #pragma unroll
        for (int g = 0; g < 4; g++)
            #pragma unroll
            for (int w = 0; w < 8; w++) acc[g][w] = 0.0f;

        for (int kp = 0; kp < CE; kp++) {
            float2 wv[4];
            #pragma unroll
            for (int g = 0; g < 4; g++) wv[g] = WT2c[kp * GC + g * CE + j];
            #pragma unroll
            for (int w = 0; w < 8; w++) {
                float2 xv = *(const float2*)&xh[w][2 * kp];
                #pragma unroll
                for (int g = 0; g < 4; g++)
                    acc[g][w] = fmaf(wv[g].y, xv.y, fmaf(wv[g].x, xv.x, acc[g][w]));
            }
        }
        __syncthreads();

        #pragma unroll
        for (int w = 0; w < 8; w++) {
            float iv = sigm(acc[0][w] + bias[0]);
            float fv = sigm(acc[1][w] + bias[1]);
            float gv = tanhf(acc[2][w] + bias[2]);
            float ov = sigm(acc[3][w] + bias[3]);
            c[w] = fv * c[w] + iv * gv;
            float h = ov * tanhf(c[w]);
            xh[w][CE + j] = h;
            if (t == len[w] - 1) last_out[(wbase + w) * CE + j] = h;
        }
    }
}

// ---------- fused word-LSTM: wordin producers + persistent recurrence (v10) ----------
// v10 = v9 (mirrored ring, single barrier, proven 4.51 ms) + ONE change:
//  * depth-2 staggered global poll. Two outstanding sample sets (P, Q) per
//    address alternate: consume P while Q is in flight, reissue, swap. This
//    halves the sampling interval of the poll (~600cy load round trip ->
//    ~300cy effective), shrinking the max-over-128-WGs detect tail that
//    quantizes the step period. (v8 bundled this with per-chunk LDS acquire
//    spins — the spins' serialized lgkmcnt drains are believed to be the 3x
//    regression; this round isolates the poll change on the good base.)
__global__ void __launch_bounds__(512, 2) fused_word_kernel(
    const float* __restrict__ Whh,            // [4096][1024]
    const int* __restrict__ word_idxs,
    const float* __restrict__ word_emb,       // [50000][512]
    const float* __restrict__ last,           // [2048][256]
    const float2* __restrict__ WT2w,          // [384][4096] k-pairs
    const float* __restrict__ bih,            // [4096]
    const float* __restrict__ bhh,            // [4096]
    float* __restrict__ in_gates,             // [2048][4096]
    unsigned long long* __restrict__ ring,    // [NMIR][3][1024] tagged h
    unsigned int* __restrict__ flags,         // [256] row-group ready counters
    float* __restrict__ out)                  // [2048][1024]
{
    __shared__ float smem[8 * KW];            // 24 KB (wordin xh / rnn hbb overlay)
    const int tid = threadIdx.x;

    if (blockIdx.x >= NWG_RNN) {
        // ---------------- wordin producer role ----------------
        const int nb    = blockIdx.x - NWG_RNN;  // 0..511
        const int grp   = nb >> 1;               // 0..255: rows 8*grp..8*grp+8
        const int half  = nb & 1;
        const int jj    = tid & 255;
        const int gh    = tid >> 8;              // 0/1
        const int rb2   = half * 2 + gh;         // gate quarter 0..3
        const int wbase = grp * 8;
        float (*xh)[KW] = (float(*)[KW])smem;

        for (int w = 0; w < 8; w++) {
            int wi = word_idxs[wbase + w];
            xh[w][tid] = word_emb[(size_t)wi * WE + tid];
            if (tid < 256) xh[w][WE + tid] = last[(wbase + w) * CE + tid];
        }
        __syncthreads();

        float acc[4][8];
        #pragma unroll
        for (int g = 0; g < 4; g++)
            #pragma unroll
            for (int w = 0; w < 8; w++) acc[g][w] = 0.0f;

        for (int kp = 0; kp < KW / 2; kp++) {    // 384 pairs
            float2 wv[4];
            #pragma unroll
            for (int g = 0; g < 4; g++) wv[g] = WT2w[(size_t)kp * GW + rb2 * GC + g * CE + jj];
            #pragma unroll
            for (int w = 0; w < 8; w++) {
                float2 xv = *(const float2*)&xh[w][2 * kp];
                #pragma unroll
                for (int g = 0; g < 4; g++)
                    acc[g][w] = fmaf(wv[g].y, xv.y, fmaf(wv[g].x, xv.x, acc[g][w]));
            }
        }

        // write-through (agent-scope) stores so the recurrence's bypassing loads
        // see them without any cache-coherence dance
        #pragma unroll
        for (int g = 0; g < 4; g++) {
            int row = rb2 * GC + g * CE + jj;
            float bias = bih[row] + bhh[row];
            #pragma unroll
            for (int w = 0; w < 8; w++)
                __hip_atomic_store(in_gates + (size_t)(wbase + w) * GW + row,
                                   acc[g][w] + bias,
                                   __ATOMIC_RELAXED, __HIP_MEMORY_SCOPE_AGENT);
        }
        __syncthreads();   // drains vmcnt -> all stores retired
        if (tid == 0)
            __hip_atomic_fetch_add(flags + grp, 1u,
                                   __ATOMIC_RELEASE, __HIP_MEMORY_SCOPE_AGENT);
        return;
    }

    // ---------------- recurrence role ----------------
    const int v = tid >> 6;                   // wave 0..7
    const int l = tid & 63;
    const int unit = blockIdx.x * 8 + v;
    float (*hbb)[HDIM] = (float(*)[HDIM])smem;   // [2][1024] in first 8 KB
    // this WG's poll mirror
    const unsigned long long* ring_my = ring + (size_t)(blockIdx.x & (NMIR - 1)) * RING_U64;

    // resident weights: all 4 gates of this wave's unit, full K
    // w[g][cc] = Whh[g*H+unit][cc*256 + l*4 .. +3]
    f32x4 w[4][4];
    #pragma unroll
    for (int g = 0; g < 4; g++)
        #pragma unroll
        for (int cc = 0; cc < 4; cc++)
            w[g][cc] = *(const f32x4*)(Whh + (size_t)(g * HDIM + unit) * HDIM
                                       + cc * 256 + l * 4);
    #pragma unroll
    for (int g = 0; g < 4; g++)
        #pragma unroll
        for (int cc = 0; cc < 4; cc++)
            asm volatile("" : "+v"(w[g][cc]));

    float c_reg = 0.0f;                       // maintained identically on lanes 0..3

    for (int t = 0; t < S_WORDS; t++) {
        // gate on in_gates availability once per 8-row group
        if ((t & 7) == 0) {
            const unsigned int* fl = flags + (t >> 3);
            while (LD_AGENT(fl) < 2u) {}
        }

        // prefetch this unit's 4 input-gate contributions (lanes 0..3); each of
        // lanes 0..3 gets the full set to run the elementwise tail redundantly.
        float ing0 = 0.f, ing1 = 0.f, ing2 = 0.f, ing3 = 0.f;
        if (l < 4) {
            const float* ig = in_gates + (size_t)t * GW + unit;
            ing0 = LD_AGENT(ig + 0 * HDIM);
            ing1 = LD_AGENT(ig + 1 * HDIM);
            ing2 = LD_AGENT(ig + 2 * HDIM);
            ing3 = LD_AGENT(ig + 3 * HDIM);
        }

        // ---- depth-2 staggered, incremental poll of this wave's 128-entry
        //      slice of our mirror: two outstanding sample sets halve the
        //      sampling interval ----
        const unsigned long long* sA = ring_my + (size_t)(t % 3) * HDIM + v * 128 + l;
        const unsigned long long* sB = sA + 64;
        unsigned long long p0 = LD_AGENT(sA), p1 = LD_AGENT(sB);
        unsigned long long q0 = LD_AGENT(sA), q1 = LD_AGENT(sB);
        bool ok0 = false, ok1 = false;
        unsigned long long h0 = 0, h1 = 0;
        const unsigned tt = (unsigned)t;
        for (;;) {
            if (!ok0 && (unsigned)(p0 >> 32) == tt) { h0 = p0; ok0 = true; }
            if (!ok1 && (unsigned)(p1 >> 32) == tt) { h1 = p1; ok1 = true; }
            if (__all(ok0 && ok1)) break;
            if (!ok0) p0 = LD_AGENT(sA);
            if (!ok1) p1 = LD_AGENT(sB);
            if (!ok0 && (unsigned)(q0 >> 32) == tt) { h0 = q0; ok0 = true; }
            if (!ok1 && (unsigned)(q1 >> 32) == tt) { h1 = q1; ok1 = true; }
            if (__all(ok0 && ok1)) break;
            if (!ok0) q0 = LD_AGENT(sA);
            if (!ok1) q1 = LD_AGENT(sB);
        }
        {
            union { unsigned u32; float f; } c0, c1;
            c0.u32 = (unsigned)h0; c1.u32 = (unsigned)h1;
            hbb[t & 1][v * 128 + l]      = c0.f;
            hbb[t & 1][v * 128 + 64 + l] = c1.f;
        }
        __syncthreads();                      // single barrier per step

        // all 4 gates of this unit over full K: 64 FMA/lane
        float acc0 = 0.f, acc1 = 0.f, acc2 = 0.f, acc3 = 0.f;
        const float* hb = hbb[t & 1];
        #pragma unroll
        for (int cc = 0; cc < 4; cc++) {
            f32x4 hv = *(const f32x4*)&hb[cc * 256 + l * 4];
            #pragma unroll
            for (int e = 0; e < 4; e++) {
                acc0 = fmaf(w[0][cc][e], hv[e], acc0);
                acc1 = fmaf(w[1][cc][e], hv[e], acc1);
                acc2 = fmaf(w[2][cc][e], hv[e], acc2);
                acc3 = fmaf(w[3][cc][e], hv[e], acc3);
            }
        }
        #pragma unroll
        for (int off = 32; off >= 1; off >>= 1) {   // butterfly allreduce:
            acc0 += __shfl_xor(acc0, off, 64);      // all lanes end with totals
            acc1 += __shfl_xor(acc1, off, 64);
            acc2 += __shfl_xor(acc2, off, 64);
            acc3 += __shfl_xor(acc3, off, 64);
        }

        if (l < 4) {                          // redundant elementwise on lanes 0..3
            float iv = sigm(acc0 + ing0);
            float fv = sigm(acc1 + ing1);
            float gv = tanh_fast(acc2 + ing2);
            float ov = sigm(acc3 + ing3);
            c_reg = fv * c_reg + iv * gv;
            float h = ov * tanh_fast(c_reg);
            union { float f; unsigned u32; } cv; cv.f = h;
            unsigned long long pv =
                ((unsigned long long)(unsigned)(t + 1) << 32) | (unsigned long long)cv.u32;
            // lane l publishes to mirror l: ONE store instruction, 4 mirrors
            __hip_atomic_store(ring + (size_t)l * RING_U64
                                    + (size_t)((t + 1) % 3) * HDIM + unit, pv,
                               __ATOMIC_RELAXED, __HIP_MEMORY_SCOPE_AGENT);
            if (l == 0) out[(size_t)t * HDIM + unit] = h;
        }
        // No trailing barrier: hbb double-buffered; wave v rewrites
        // hbb[t&1][slice v] at t+2 only after detecting h(t+2) tags, which
        // transitively implies all units published h(t+1), which implies every
        // sibling wave passed barrier(t+1), i.e. finished step t's hbb reads.
    }
}

extern "C" void kernel_launch(void* const* d_in, const int* in_sizes, int n_in,
                              void* d_out, int out_size, void* d_ws, size_t ws_size,
                              hipStream_t stream) {
    const int* word_idxs = (const int*)d_in[0];
    const int* char_idxs = (const int*)d_in[1];
    const int* char_lens = (const int*)d_in[2];
    const float* char_emb = (const float*)d_in[3];
    const float* word_emb = (const float*)d_in[4];
    const float* Wih_c = (const float*)d_in[5];
    const float* Whh_c = (const float*)d_in[6];
    const float* bih_c = (const float*)d_in[7];
    const float* bhh_c = (const float*)d_in[8];
    const float* Wih_w = (const float*)d_in[9];
    const float* Whh_w = (const float*)d_in[10];
    const float* bih_w = (const float*)d_in[11];
    const float* bhh_w = (const float*)d_in[12];

    char* ws = (char*)d_ws;
    float*  in_gates = (float*)(ws + IN_GATES_OFF);
    float*  last     = (float*)(ws + LAST_OFF);
    float2* WT2c     = (float2*)(ws + WT2C_OFF);
    float2* WT2w     = (float2*)(ws + WT2W_OFF);
    unsigned long long* ring = (unsigned long long*)(ws + RING_OFF);
    unsigned int* flags      = (unsigned int*)(ws + FLAGS_OFF);

    hipLaunchKernelGGL(prep_c_kernel, dim3(1024), dim3(256), 0, stream,
                       Wih_c, Whh_c, WT2c);
    hipLaunchKernelGGL(prep_w_kernel, dim3(6144), dim3(256), 0, stream,
                       Wih_w, WT2w);
    hipLaunchKernelGGL(char_lstm_kernel, dim3(256), dim3(256), 0, stream,
                       char_idxs, char_lens, char_emb, bih_c, bhh_c, WT2c, last);
    // ring mirrors + flags alias WT2c — zero only after char_lstm consumed the
    // weights. All mirrors' slot0 = {tag=0, h=0} (valid t=0 input); slots 1/2 +
    // flags start at 0.
    hipMemsetAsync(ws + RING_OFF, 0,
                   NMIR * RING_U64 * sizeof(unsigned long long) + 256 * sizeof(unsigned int),
                   stream);
    hipLaunchKernelGGL(fused_word_kernel, dim3(NWG_RNN + NWB_WIN), dim3(512), 0, stream,
                       Whh_w, word_idxs, word_emb, last, WT2w, bih_w, bhh_w,
                       in_gates, ring, flags, (float*)d_out);
}

// Round 5
// 5727.541 us; speedup vs baseline: 1.4450x; 1.4450x over previous
//
#include <hip/hip_runtime.h>
#include <stdint.h>

// Problem constants (from reference)
#define S_WORDS 2048
#define LMAX    16
#define CE      256
#define WE      512
#define HDIM    1024
#define GC      1024   // 4*CE
#define GW      4096   // 4*HDIM
#define KW      768    // WE + CE
#define NWG_RNN 128    // recurrence WGs: 8 units each, 1 unit per wave
#define NWB_WIN 512    // fused wordin producer blocks (2 per 8-row group)
#define NMIR    4      // ring mirrors (fan-in reduction 128 -> 32 pollers/line)
#define RING_U64 (3 * HDIM)   // u64 per mirror (3 slots x 1024)

// Workspace layout (bytes) — high-water 50,331,648 (48 MiB)
#define IN_GATES_OFF 0                       // 2048*4096 fp32 = 33554432
#define LAST_OFF     33554432                // 2048*256 fp32  =  2097152
#define WT2C_OFF     35651584                // 256*1024 float2 = 2097152 (char weights)
#define WT2W_OFF     37748736                // 384*4096 float2 = 12582912
// Ring mirrors + row-ready flags alias WT2c (dead after char_lstm; memset after):
#define RING_OFF     WT2C_OFF                // 4 mirrors * 3 slots * 1024 u64 = 98304
#define FLAGS_OFF    (RING_OFF + NMIR * RING_U64 * 8)  // 256 u32 = 1024

typedef float f32x4 __attribute__((ext_vector_type(4)));

#define LD_AGENT(p) __hip_atomic_load((p), __ATOMIC_RELAXED, __HIP_MEMORY_SCOPE_AGENT)

static __device__ __forceinline__ float sigm(float x) { return 1.0f / (1.0f + __expf(-x)); }
static __device__ __forceinline__ float tanh_fast(float x) {
    float ax = fminf(fabsf(x), 15.0f);
    float e  = __expf(2.0f * ax);
    float t  = (e - 1.0f) / (e + 1.0f);
    return copysignf(t, x);
}

// ---------- prep: transposed k-major float2 pairs for coalesced reads ----------
__global__ void prep_c_kernel(const float* __restrict__ Wih,
                              const float* __restrict__ Whh,
                              float2* __restrict__ WT2c) {
    int idx = blockIdx.x * blockDim.x + threadIdx.x;   // 256*1024
    if (idx >= 256 * GC) return;
    int kp = idx >> 10, row = idx & (GC - 1);
    int k = kp * 2;
    float2 v;
    if (k < CE) { v.x = Wih[row * CE + k];      v.y = Wih[row * CE + k + 1]; }
    else        { v.x = Whh[row * CE + k - CE]; v.y = Whh[row * CE + k - CE + 1]; }
    WT2c[idx] = v;
}

__global__ void prep_w_kernel(const float* __restrict__ Wih,
                              float2* __restrict__ WT2w) {
    int idx = blockIdx.x * blockDim.x + threadIdx.x;   // 384*4096
    if (idx >= 384 * GW) return;
    int kp = idx >> 12, row = idx & (GW - 1);
    float2 v;
    v.x = Wih[row * KW + 2 * kp];
    v.y = Wih[row * KW + 2 * kp + 1];
    WT2w[idx] = v;
}

// ---------- char LSTM v11: 256 blocks x 512 threads; word-split ----------
// Was 256 thr (1 wave/SIMD — zero TLP, every WT2c/L2 and xh/LDS load stalled
// the lone wave). Now thread (wh, j) = (tid>>8, tid&255) handles words
// 4wh..4wh+3 for unit j: per-thread FMA halves, 2 waves/SIMD hide latency,
// both halves share WT2c lines via L1, and the word-split keeps c[] state and
// the elementwise tail thread-local (no cross-thread gate exchange).
__global__ void __launch_bounds__(512) char_lstm_kernel(
    const int* __restrict__ char_idxs,        // [2048][16]
    const int* __restrict__ char_lens,        // [2048]
    const float* __restrict__ char_emb,       // [256][256]
    const float* __restrict__ bih,            // [1024]
    const float* __restrict__ bhh,            // [1024]
    const float2* __restrict__ WT2c,          // [256][1024] k-pairs
    float* __restrict__ last_out)             // [2048][256]
{
    __shared__ float xh[8][2 * CE];           // 16 KB
    const int j  = threadIdx.x & 255;         // unit
    const int wh = threadIdx.x >> 8;          // word half: 0 -> words 0..3, 1 -> 4..7
    const int wbase = blockIdx.x * 8 + wh * 4;

    float bias[4];
    #pragma unroll
    for (int g = 0; g < 4; g++) bias[g] = bih[g * CE + j] + bhh[g * CE + j];

    int len[4];
    float c[4];
    #pragma unroll
    for (int w = 0; w < 4; w++) {
        c[w] = 0.0f;
        xh[wh * 4 + w][CE + j] = 0.0f;        // h_{-1} = 0
        len[w] = char_lens[wbase + w];
    }

    for (int t = 0; t < LMAX; t++) {
        #pragma unroll
        for (int w = 0; w < 4; w++) {
            int ci = char_idxs[(wbase + w) * LMAX + t];
            xh[wh * 4 + w][j] = char_emb[ci * CE + j];
        }
        __syncthreads();

        float acc[4][4];
        #pragma unroll
        for (int g = 0; g < 4; g++)
            #pragma unroll
            for (int w = 0; w < 4; w++) acc[g][w] = 0.0f;

        for (int kp = 0; kp < CE; kp++) {     // 256 pairs over K=512
            float2 wv[4];
            #pragma unroll
            for (int g = 0; g < 4; g++) wv[g] = WT2c[kp * GC + g * CE + j];
            #pragma unroll
            for (int w = 0; w < 4; w++) {
                float2 xv = *(const float2*)&xh[wh * 4 + w][2 * kp];
                #pragma unroll
                for (int g = 0; g < 4; g++)
                    acc[g][w] = fmaf(wv[g].y, xv.y, fmaf(wv[g].x, xv.x, acc[g][w]));
            }
        }
        __syncthreads();                      // all reads of xh done

        #pragma unroll
        for (int w = 0; w < 4; w++) {
            float iv = sigm(acc[0][w] + bias[0]);
            float fv = sigm(acc[1][w] + bias[1]);
            float gv = tanhf(acc[2][w] + bias[2]);
            float ov = sigm(acc[3][w] + bias[3]);
            c[w] = fv * c[w] + iv * gv;
            float h = ov * tanhf(c[w]);
            xh[wh * 4 + w][CE + j] = h;
            if (t == len[w] - 1) last_out[(wbase + w) * CE + j] = h;
        }
    }
}

// ---------- fused word-LSTM: wordin producers + persistent recurrence (v9 rnn) ----------
// rnn = exact v9 (mirrored ring, single barrier, depth-1 incremental poll —
// proven 4.51 ms). v10's depth-2 same-address poll regressed 60%: consuming the
// youngest outstanding load forces vmcnt(0), so stagger gains nothing and the
// doubled request stream + serialized drains inflate the loop. Depth-1 only.
__global__ void __launch_bounds__(512, 2) fused_word_kernel(
    const float* __restrict__ Whh,            // [4096][1024]
    const int* __restrict__ word_idxs,
    const float* __restrict__ word_emb,       // [50000][512]
    const float* __restrict__ last,           // [2048][256]
    const float2* __restrict__ WT2w,          // [384][4096] k-pairs
    const float* __restrict__ bih,            // [4096]
    const float* __restrict__ bhh,            // [4096]
    float* __restrict__ in_gates,             // [2048][4096]
    unsigned long long* __restrict__ ring,    // [NMIR][3][1024] tagged h
    unsigned int* __restrict__ flags,         // [256] row-group ready counters
    float* __restrict__ out)                  // [2048][1024]
{
    __shared__ float smem[8 * KW];            // 24 KB (wordin xh / rnn hbb overlay)
    const int tid = threadIdx.x;

    if (blockIdx.x >= NWG_RNN) {
        // ---------------- wordin producer role ----------------
        const int nb    = blockIdx.x - NWG_RNN;  // 0..511
        const int grp   = nb >> 1;               // 0..255: rows 8*grp..8*grp+8
        const int half  = nb & 1;
        const int jj    = tid & 255;
        const int gh    = tid >> 8;              // 0/1
        const int rb2   = half * 2 + gh;         // gate quarter 0..3
        const int wbase = grp * 8;
        float (*xh)[KW] = (float(*)[KW])smem;

        for (int w = 0; w < 8; w++) {
            int wi = word_idxs[wbase + w];
            xh[w][tid] = word_emb[(size_t)wi * WE + tid];
            if (tid < 256) xh[w][WE + tid] = last[(wbase + w) * CE + tid];
        }
        __syncthreads();

        float acc[4][8];
        #pragma unroll
        for (int g = 0; g < 4; g++)
            #pragma unroll
            for (int w = 0; w < 8; w++) acc[g][w] = 0.0f;

        for (int kp = 0; kp < KW / 2; kp++) {    // 384 pairs
            float2 wv[4];
            #pragma unroll
            for (int g = 0; g < 4; g++) wv[g] = WT2w[(size_t)kp * GW + rb2 * GC + g * CE + jj];
            #pragma unroll
            for (int w = 0; w < 8; w++) {
                float2 xv = *(const float2*)&xh[w][2 * kp];
                #pragma unroll
                for (int g = 0; g < 4; g++)
                    acc[g][w] = fmaf(wv[g].y, xv.y, fmaf(wv[g].x, xv.x, acc[g][w]));
            }
        }

        // write-through (agent-scope) stores so the recurrence's bypassing loads
        // see them without any cache-coherence dance
        #pragma unroll
        for (int g = 0; g < 4; g++) {
            int row = rb2 * GC + g * CE + jj;
            float bias = bih[row] + bhh[row];
            #pragma unroll
            for (int w = 0; w < 8; w++)
                __hip_atomic_store(in_gates + (size_t)(wbase + w) * GW + row,
                                   acc[g][w] + bias,
                                   __ATOMIC_RELAXED, __HIP_MEMORY_SCOPE_AGENT);
        }
        __syncthreads();   // drains vmcnt -> all stores retired
        if (tid == 0)
            __hip_atomic_fetch_add(flags + grp, 1u,
                                   __ATOMIC_RELEASE, __HIP_MEMORY_SCOPE_AGENT);
        return;
    }

    // ---------------- recurrence role ----------------
    const int v = tid >> 6;                   // wave 0..7
    const int l = tid & 63;
    const int unit = blockIdx.x * 8 + v;
    float (*hbb)[HDIM] = (float(*)[HDIM])smem;   // [2][1024] in first 8 KB
    // this WG's poll mirror
    const unsigned long long* ring_my = ring + (size_t)(blockIdx.x & (NMIR - 1)) * RING_U64;

    // resident weights: all 4 gates of this wave's unit, full K
    // w[g][cc] = Whh[g*H+unit][cc*256 + l*4 .. +3]
    f32x4 w[4][4];
    #pragma unroll
    for (int g = 0; g < 4; g++)
        #pragma unroll
        for (int cc = 0; cc < 4; cc++)
            w[g][cc] = *(const f32x4*)(Whh + (size_t)(g * HDIM + unit) * HDIM
                                       + cc * 256 + l * 4);
    #pragma unroll
    for (int g = 0; g < 4; g++)
        #pragma unroll
        for (int cc = 0; cc < 4; cc++)
            asm volatile("" : "+v"(w[g][cc]));

    float c_reg = 0.0f;                       // maintained identically on lanes 0..3

    for (int t = 0; t < S_WORDS; t++) {
        // gate on in_gates availability once per 8-row group
        if ((t & 7) == 0) {
            const unsigned int* fl = flags + (t >> 3);
            while (LD_AGENT(fl) < 2u) {}
        }

        // prefetch this unit's 4 input-gate contributions (lanes 0..3); each of
        // lanes 0..3 gets the full set to run the elementwise tail redundantly.
        float ing0 = 0.f, ing1 = 0.f, ing2 = 0.f, ing3 = 0.f;
        if (l < 4) {
            const float* ig = in_gates + (size_t)t * GW + unit;
            ing0 = LD_AGENT(ig + 0 * HDIM);
            ing1 = LD_AGENT(ig + 1 * HDIM);
            ing2 = LD_AGENT(ig + 2 * HDIM);
            ing3 = LD_AGENT(ig + 3 * HDIM);
        }

        // incremental depth-1 poll of this wave's 128-entry slice of our mirror
        const unsigned long long* slot = ring_my + (size_t)(t % 3) * HDIM + v * 128;
        unsigned long long a0 = 0, a1 = 0;
        bool ok0 = false, ok1 = false;
        do {
            if (!ok0) {
                a0 = LD_AGENT(slot + l);
                ok0 = ((unsigned)(a0 >> 32) == (unsigned)t);
            }
            if (!ok1) {
                a1 = LD_AGENT(slot + 64 + l);
                ok1 = ((unsigned)(a1 >> 32) == (unsigned)t);
            }
        } while (!__all(ok0 && ok1));
        {
            union { unsigned u32; float f; } c0, c1;
            c0.u32 = (unsigned)a0; c1.u32 = (unsigned)a1;
            hbb[t & 1][v * 128 + l]      = c0.f;
            hbb[t & 1][v * 128 + 64 + l] = c1.f;
        }
        __syncthreads();                      // single barrier per step

        // all 4 gates of this unit over full K: 64 FMA/lane
        float acc0 = 0.f, acc1 = 0.f, acc2 = 0.f, acc3 = 0.f;
        const float* hb = hbb[t & 1];
        #pragma unroll
        for (int cc = 0; cc < 4; cc++) {
            f32x4 hv = *(const f32x4*)&hb[cc * 256 + l * 4];
            #pragma unroll
            for (int e = 0; e < 4; e++) {
                acc0 = fmaf(w[0][cc][e], hv[e], acc0);
                acc1 = fmaf(w[1][cc][e], hv[e], acc1);
                acc2 = fmaf(w[2][cc][e], hv[e], acc2);
                acc3 = fmaf(w[3][cc][e], hv[e], acc3);
            }
        }
        #pragma unroll
        for (int off = 32; off >= 1; off >>= 1) {   // butterfly allreduce:
            acc0 += __shfl_xor(acc0, off, 64);      // all lanes end with totals
            acc1 += __shfl_xor(acc1, off, 64);
            acc2 += __shfl_xor(acc2, off, 64);
            acc3 += __shfl_xor(acc3, off, 64);
        }

        if (l < 4) {                          // redundant elementwise on lanes 0..3
            float iv = sigm(acc0 + ing0);
            float fv = sigm(acc1 + ing1);
            float gv = tanh_fast(acc2 + ing2);
            float ov = sigm(acc3 + ing3);
            c_reg = fv * c_reg + iv * gv;
            float h = ov * tanh_fast(c_reg);
            union { float f; unsigned u32; } cv; cv.f = h;
            unsigned long long pv =
                ((unsigned long long)(unsigned)(t + 1) << 32) | (unsigned long long)cv.u32;
            // lane l publishes to mirror l: ONE store instruction, 4 mirrors
            __hip_atomic_store(ring + (size_t)l * RING_U64
                                    + (size_t)((t + 1) % 3) * HDIM + unit, pv,
                               __ATOMIC_RELAXED, __HIP_MEMORY_SCOPE_AGENT);
            if (l == 0) out[(size_t)t * HDIM + unit] = h;
        }
        // No trailing barrier: hbb double-buffered; wave v rewrites
        // hbb[t&1][slice v] at t+2 only after detecting h(t+2) tags, which
        // transitively implies all units published h(t+1), which implies every
        // sibling wave passed barrier(t+1), i.e. finished step t's hbb reads.
    }
}

extern "C" void kernel_launch(void* const* d_in, const int* in_sizes, int n_in,
                              void* d_out, int out_size, void* d_ws, size_t ws_size,
                              hipStream_t stream) {
    const int* word_idxs = (const int*)d_in[0];
    const int* char_idxs = (const int*)d_in[1];
    const int* char_lens = (const int*)d_in[2];
    const float* char_emb = (const float*)d_in[3];
    const float* word_emb = (const float*)d_in[4];
    const float* Wih_c = (const float*)d_in[5];
    const float* Whh_c = (const float*)d_in[6];
    const float* bih_c = (const float*)d_in[7];
    const float* bhh_c = (const float*)d_in[8];
    const float* Wih_w = (const float*)d_in[9];
    const float* Whh_w = (const float*)d_in[10];
    const float* bih_w = (const float*)d_in[11];
    const float* bhh_w = (const float*)d_in[12];

    char* ws = (char*)d_ws;
    float*  in_gates = (float*)(ws + IN_GATES_OFF);
    float*  last     = (float*)(ws + LAST_OFF);
    float2* WT2c     = (float2*)(ws + WT2C_OFF);
    float2* WT2w     = (float2*)(ws + WT2W_OFF);
    unsigned long long* ring = (unsigned long long*)(ws + RING_OFF);
    unsigned int* flags      = (unsigned int*)(ws + FLAGS_OFF);

    hipLaunchKernelGGL(prep_c_kernel, dim3(1024), dim3(256), 0, stream,
                       Wih_c, Whh_c, WT2c);
    hipLaunchKernelGGL(prep_w_kernel, dim3(6144), dim3(256), 0, stream,
                       Wih_w, WT2w);
    hipLaunchKernelGGL(char_lstm_kernel, dim3(256), dim3(512), 0, stream,
                       char_idxs, char_lens, char_emb, bih_c, bhh_c, WT2c, last);
    // ring mirrors + flags alias WT2c — zero only after char_lstm consumed the
    // weights. All mirrors' slot0 = {tag=0, h=0} (valid t=0 input); slots 1/2 +
    // flags start at 0.
    hipMemsetAsync(ws + RING_OFF, 0,
                   NMIR * RING_U64 * sizeof(unsigned long long) + 256 * sizeof(unsigned int),
                   stream);
    hipLaunchKernelGGL(fused_word_kernel, dim3(NWG_RNN + NWB_WIN), dim3(512), 0, stream,
                       Whh_w, word_idxs, word_emb, last, WT2w, bih_w, bhh_w,
                       in_gates, ring, flags, (float*)d_out);
}

// Round 6
// 5514.286 us; speedup vs baseline: 1.5009x; 1.0387x over previous
//
#include <hip/hip_runtime.h>
#include <stdint.h>

// Problem constants (from reference)
#define S_WORDS 2048
#define LMAX    16
#define CE      256
#define WE      512
#define HDIM    1024
#define GC      1024   // 4*CE
#define GW      4096   // 4*HDIM
#define KW      768    // WE + CE
#define NWG_RNN 128    // recurrence WGs: 8 units each, 1 unit per wave
#define NWB_WIN 512    // fused wordin producer blocks (2 per 8-row group)
#define NMIR    4      // ring mirrors (fan-in reduction 128 -> 32 pollers/line)
#define RING_U64 (3 * HDIM)   // u64 per mirror (3 slots x 1024)

// Workspace layout (bytes) — high-water 50,331,648 (48 MiB)
#define IN_GATES_OFF 0                       // 2048*4096 fp32 = 33554432
#define LAST_OFF     33554432                // 2048*256 fp32  =  2097152
#define WT2C_OFF     35651584                // 256*1024 float2 = 2097152 (char weights)
#define WT2W_OFF     37748736                // 384*4096 float2 = 12582912
// Ring mirrors + row-ready flags alias WT2c (dead after char_lstm; memset after):
#define RING_OFF     WT2C_OFF                // 4 mirrors * 3 slots * 1024 u64 = 98304
#define FLAGS_OFF    (RING_OFF + NMIR * RING_U64 * 8)  // 256 u32 = 1024

typedef float f32x4 __attribute__((ext_vector_type(4)));

#define LD_AGENT(p) __hip_atomic_load((p), __ATOMIC_RELAXED, __HIP_MEMORY_SCOPE_AGENT)

static __device__ __forceinline__ float sigm(float x) { return 1.0f / (1.0f + __expf(-x)); }
static __device__ __forceinline__ float tanh_fast(float x) {
    float ax = fminf(fabsf(x), 15.0f);
    float e  = __expf(2.0f * ax);
    float t  = (e - 1.0f) / (e + 1.0f);
    return copysignf(t, x);
}

// ---------- prep: transposed k-major float2 pairs for coalesced reads ----------
__global__ void prep_c_kernel(const float* __restrict__ Wih,
                              const float* __restrict__ Whh,
                              float2* __restrict__ WT2c) {
    int idx = blockIdx.x * blockDim.x + threadIdx.x;   // 256*1024
    if (idx >= 256 * GC) return;
    int kp = idx >> 10, row = idx & (GC - 1);
    int k = kp * 2;
    float2 v;
    if (k < CE) { v.x = Wih[row * CE + k];      v.y = Wih[row * CE + k + 1]; }
    else        { v.x = Whh[row * CE + k - CE]; v.y = Whh[row * CE + k - CE + 1]; }
    WT2c[idx] = v;
}

__global__ void prep_w_kernel(const float* __restrict__ Wih,
                              float2* __restrict__ WT2w) {
    int idx = blockIdx.x * blockDim.x + threadIdx.x;   // 384*4096
    if (idx >= 384 * GW) return;
    int kp = idx >> 12, row = idx & (GW - 1);
    float2 v;
    v.x = Wih[row * KW + 2 * kp];
    v.y = Wih[row * KW + 2 * kp + 1];
    WT2w[idx] = v;
}

// ---------- char LSTM v12: 256 blocks x 1024 threads; GATE-split ----------
// v11's word-split doubled the per-thread weight-load stream and regressed.
// Gate-split instead: thread (g, j) = (tid>>8, tid&255) owns gate g of unit j
// over the FULL K=512. Weight loads per thread drop 4x (one float2/kp), total
// weight traffic per block unchanged (2 MB/step), TLP = 4 waves/SIMD hides L2
// latency, and each thread's gate value is complete — no K-reduction. The 4
// gates of unit j are exchanged through padded LDS (gex, 8 writes + 8 reads
// per thread per step); elementwise + c-state stay thread-local (thread (g,j)
// owns words 2g, 2g+1). Same 2 barriers/step as the original.
__global__ void __launch_bounds__(1024, 1) char_lstm_kernel(
    const int* __restrict__ char_idxs,        // [2048][16]
    const int* __restrict__ char_lens,        // [2048]
    const float* __restrict__ char_emb,       // [256][256]
    const float* __restrict__ bih,            // [1024]
    const float* __restrict__ bhh,            // [1024]
    const float2* __restrict__ WT2c,          // [256][1024] k-pairs
    float* __restrict__ last_out)             // [2048][256]
{
    __shared__ float xh[8][2 * CE];           // 16 KB: [word][x(256) | h(256)]
    __shared__ float gex[4][256][9];          // 36 KB (pad 9: j*9 invertible mod 32)
    const int j = threadIdx.x & 255;          // unit
    const int g = threadIdx.x >> 8;           // gate 0..3; also word-pair owner
    const int wbase = blockIdx.x * 8;

    const float bias = bih[g * CE + j] + bhh[g * CE + j];   // own gate row only

    int len[2];
    float c[2] = {0.0f, 0.0f};
    len[0] = char_lens[wbase + 2 * g];
    len[1] = char_lens[wbase + 2 * g + 1];
    xh[2 * g][CE + j]     = 0.0f;             // h_{-1} = 0 (words 2g, 2g+1)
    xh[2 * g + 1][CE + j] = 0.0f;

    const float2* __restrict__ wrow = WT2c + g * CE + j;    // row g*256+j, kp-major

    for (int t = 0; t < LMAX; t++) {
        // gather x(t) for this thread's 2 words (x-part last read before B2(t-1))
        {
            int ci0 = char_idxs[(wbase + 2 * g) * LMAX + t];
            int ci1 = char_idxs[(wbase + 2 * g + 1) * LMAX + t];
            xh[2 * g][j]     = char_emb[ci0 * CE + j];
            xh[2 * g + 1][j] = char_emb[ci1 * CE + j];
        }
        __syncthreads();                      // B1: x(t) + h(t-1) visible

        float acc[8];
        #pragma unroll
        for (int w = 0; w < 8; w++) acc[w] = 0.0f;

        #pragma unroll 2
        for (int kq = 0; kq < 128; kq++) {    // 2 k-pairs (4 k) per iter
            float2 wv0 = wrow[(size_t)(2 * kq) * GC];
            float2 wv1 = wrow[(size_t)(2 * kq + 1) * GC];
            #pragma unroll
            for (int w = 0; w < 8; w++) {
                f32x4 xv = *(const f32x4*)&xh[w][4 * kq];   // wave-broadcast
                acc[w] = fmaf(wv0.x, xv[0],
                         fmaf(wv0.y, xv[1],
                         fmaf(wv1.x, xv[2],
                         fmaf(wv1.y, xv[3], acc[w]))));
            }
        }

        #pragma unroll
        for (int w = 0; w < 8; w++) gex[g][j][w] = acc[w] + bias;
        __syncthreads();                      // B2: gex ready; all xh reads done

        // elementwise for words 2g, 2g+1 (c-state thread-local)
        #pragma unroll
        for (int ww = 0; ww < 2; ww++) {
            int w = 2 * g + ww;
            float gi = gex[0][j][w];
            float gf = gex[1][j][w];
            float gg = gex[2][j][w];
            float go = gex[3][j][w];
            float iv = sigm(gi);
            float fv = sigm(gf);
            float gv = tanhf(gg);
            float ov = sigm(go);
            c[ww] = fv * c[ww] + iv * gv;
            float h = ov * tanhf(c[ww]);
            xh[w][CE + j] = h;                // read by FMA(t+1) after B1(t+1)
            if (t == len[ww] - 1) last_out[(wbase + w) * CE + j] = h;
        }
        // gather(t+1) writes x-part only; FMA(t) reads finished before B2 — safe
    }
}

// ---------- fused word-LSTM: wordin producers + persistent recurrence (v9 rnn) ----------
// rnn = exact v9 (mirrored ring, single barrier, depth-1 incremental poll —
// proven 4.51-4.54 ms). v10's depth-2 same-address poll regressed 60%:
// consuming the youngest outstanding load forces vmcnt(0), so stagger gains
// nothing and the doubled request stream serializes drains. Depth-1 only.
__global__ void __launch_bounds__(512, 2) fused_word_kernel(
    const float* __restrict__ Whh,            // [4096][1024]
    const int* __restrict__ word_idxs,
    const float* __restrict__ word_emb,       // [50000][512]
    const float* __restrict__ last,           // [2048][256]
    const float2* __restrict__ WT2w,          // [384][4096] k-pairs
    const float* __restrict__ bih,            // [4096]
    const float* __restrict__ bhh,            // [4096]
    float* __restrict__ in_gates,             // [2048][4096]
    unsigned long long* __restrict__ ring,    // [NMIR][3][1024] tagged h
    unsigned int* __restrict__ flags,         // [256] row-group ready counters
    float* __restrict__ out)                  // [2048][1024]
{
    __shared__ float smem[8 * KW];            // 24 KB (wordin xh / rnn hbb overlay)
    const int tid = threadIdx.x;

    if (blockIdx.x >= NWG_RNN) {
        // ---------------- wordin producer role ----------------
        const int nb    = blockIdx.x - NWG_RNN;  // 0..511
        const int grp   = nb >> 1;               // 0..255: rows 8*grp..8*grp+8
        const int half  = nb & 1;
        const int jj    = tid & 255;
        const int gh    = tid >> 8;              // 0/1
        const int rb2   = half * 2 + gh;         // gate quarter 0..3
        const int wbase = grp * 8;
        float (*xh)[KW] = (float(*)[KW])smem;

        for (int w = 0; w < 8; w++) {
            int wi = word_idxs[wbase + w];
            xh[w][tid] = word_emb[(size_t)wi * WE + tid];
            if (tid < 256) xh[w][WE + tid] = last[(wbase + w) * CE + tid];
        }
        __syncthreads();

        float acc[4][8];
        #pragma unroll
        for (int g = 0; g < 4; g++)
            #pragma unroll
            for (int w = 0; w < 8; w++) acc[g][w] = 0.0f;

        for (int kp = 0; kp < KW / 2; kp++) {    // 384 pairs
            float2 wv[4];
            #pragma unroll
            for (int g = 0; g < 4; g++) wv[g] = WT2w[(size_t)kp * GW + rb2 * GC + g * CE + jj];
            #pragma unroll
            for (int w = 0; w < 8; w++) {
                float2 xv = *(const float2*)&xh[w][2 * kp];
                #pragma unroll
                for (int g = 0; g < 4; g++)
                    acc[g][w] = fmaf(wv[g].y, xv.y, fmaf(wv[g].x, xv.x, acc[g][w]));
            }
        }

        // write-through (agent-scope) stores so the recurrence's bypassing loads
        // see them without any cache-coherence dance
        #pragma unroll
        for (int g = 0; g < 4; g++) {
            int row = rb2 * GC + g * CE + jj;
            float bias = bih[row] + bhh[row];
            #pragma unroll
            for (int w = 0; w < 8; w++)
                __hip_atomic_store(in_gates + (size_t)(wbase + w) * GW + row,
                                   acc[g][w] + bias,
                                   __ATOMIC_RELAXED, __HIP_MEMORY_SCOPE_AGENT);
        }
        __syncthreads();   // drains vmcnt -> all stores retired
        if (tid == 0)
            __hip_atomic_fetch_add(flags + grp, 1u,
                                   __ATOMIC_RELEASE, __HIP_MEMORY_SCOPE_AGENT);
        return;
    }

    // ---------------- recurrence role ----------------
    const int v = tid >> 6;                   // wave 0..7
    const int l = tid & 63;
    const int unit = blockIdx.x * 8 + v;
    float (*hbb)[HDIM] = (float(*)[HDIM])smem;   // [2][1024] in first 8 KB
    // this WG's poll mirror
    const unsigned long long* ring_my = ring + (size_t)(blockIdx.x & (NMIR - 1)) * RING_U64;

    // resident weights: all 4 gates of this wave's unit, full K
    // w[g][cc] = Whh[g*H+unit][cc*256 + l*4 .. +3]
    f32x4 w[4][4];
    #pragma unroll
    for (int g = 0; g < 4; g++)
        #pragma unroll
        for (int cc = 0; cc < 4; cc++)
            w[g][cc] = *(const f32x4*)(Whh + (size_t)(g * HDIM + unit) * HDIM
                                       + cc * 256 + l * 4);
    #pragma unroll
    for (int g = 0; g < 4; g++)
        #pragma unroll
        for (int cc = 0; cc < 4; cc++)
            asm volatile("" : "+v"(w[g][cc]));

    float c_reg = 0.0f;                       // maintained identically on lanes 0..3

    for (int t = 0; t < S_WORDS; t++) {
        // gate on in_gates availability once per 8-row group
        if ((t & 7) == 0) {
            const unsigned int* fl = flags + (t >> 3);
            while (LD_AGENT(fl) < 2u) {}
        }

        // prefetch this unit's 4 input-gate contributions (lanes 0..3); each of
        // lanes 0..3 gets the full set to run the elementwise tail redundantly.
        float ing0 = 0.f, ing1 = 0.f, ing2 = 0.f, ing3 = 0.f;
        if (l < 4) {
            const float* ig = in_gates + (size_t)t * GW + unit;
            ing0 = LD_AGENT(ig + 0 * HDIM);
            ing1 = LD_AGENT(ig + 1 * HDIM);
            ing2 = LD_AGENT(ig + 2 * HDIM);
            ing3 = LD_AGENT(ig + 3 * HDIM);
        }

        // incremental depth-1 poll of this wave's 128-entry slice of our mirror
        const unsigned long long* slot = ring_my + (size_t)(t % 3) * HDIM + v * 128;
        unsigned long long a0 = 0, a1 = 0;
        bool ok0 = false, ok1 = false;
        do {
            if (!ok0) {
                a0 = LD_AGENT(slot + l);
                ok0 = ((unsigned)(a0 >> 32) == (unsigned)t);
            }
            if (!ok1) {
                a1 = LD_AGENT(slot + 64 + l);
                ok1 = ((unsigned)(a1 >> 32) == (unsigned)t);
            }
        } while (!__all(ok0 && ok1));
        {
            union { unsigned u32; float f; } c0, c1;
            c0.u32 = (unsigned)a0; c1.u32 = (unsigned)a1;
            hbb[t & 1][v * 128 + l]      = c0.f;
            hbb[t & 1][v * 128 + 64 + l] = c1.f;
        }
        __syncthreads();                      // single barrier per step

        // all 4 gates of this unit over full K: 64 FMA/lane
        float acc0 = 0.f, acc1 = 0.f, acc2 = 0.f, acc3 = 0.f;
        const float* hb = hbb[t & 1];
        #pragma unroll
        for (int cc = 0; cc < 4; cc++) {
            f32x4 hv = *(const f32x4*)&hb[cc * 256 + l * 4];
            #pragma unroll
            for (int e = 0; e < 4; e++) {
                acc0 = fmaf(w[0][cc][e], hv[e], acc0);
                acc1 = fmaf(w[1][cc][e], hv[e], acc1);
                acc2 = fmaf(w[2][cc][e], hv[e], acc2);
                acc3 = fmaf(w[3][cc][e], hv[e], acc3);
            }
        }
        #pragma unroll
        for (int off = 32; off >= 1; off >>= 1) {   // butterfly allreduce:
            acc0 += __shfl_xor(acc0, off, 64);      // all lanes end with totals
            acc1 += __shfl_xor(acc1, off, 64);
            acc2 += __shfl_xor(acc2, off, 64);
            acc3 += __shfl_xor(acc3, off, 64);
        }

        if (l < 4) {                          // redundant elementwise on lanes 0..3
            float iv = sigm(acc0 + ing0);
            float fv = sigm(acc1 + ing1);
            float gv = tanh_fast(acc2 + ing2);
            float ov = sigm(acc3 + ing3);
            c_reg = fv * c_reg + iv * gv;
            float h = ov * tanh_fast(c_reg);
            union { float f; unsigned u32; } cv; cv.f = h;
            unsigned long long pv =
                ((unsigned long long)(unsigned)(t + 1) << 32) | (unsigned long long)cv.u32;
            // lane l publishes to mirror l: ONE store instruction, 4 mirrors
            __hip_atomic_store(ring + (size_t)l * RING_U64
                                    + (size_t)((t + 1) % 3) * HDIM + unit, pv,
                               __ATOMIC_RELAXED, __HIP_MEMORY_SCOPE_AGENT);
            if (l == 0) out[(size_t)t * HDIM + unit] = h;
        }
        // No trailing barrier: hbb double-buffered; wave v rewrites
        // hbb[t&1][slice v] at t+2 only after detecting h(t+2) tags, which
        // transitively implies all units published h(t+1), which implies every
        // sibling wave passed barrier(t+1), i.e. finished step t's hbb reads.
    }
}

extern "C" void kernel_launch(void* const* d_in, const int* in_sizes, int n_in,
                              void* d_out, int out_size, void* d_ws, size_t ws_size,
                              hipStream_t stream) {
    const int* word_idxs = (const int*)d_in[0];
    const int* char_idxs = (const int*)d_in[1];
    const int* char_lens = (const int*)d_in[2];
    const float* char_emb = (const float*)d_in[3];
    const float* word_emb = (const float*)d_in[4];
    const float* Wih_c = (const float*)d_in[5];
    const float* Whh_c = (const float*)d_in[6];
    const float* bih_c = (const float*)d_in[7];
    const float* bhh_c = (const float*)d_in[8];
    const float* Wih_w = (const float*)d_in[9];
    const float* Whh_w = (const float*)d_in[10];
    const float* bih_w = (const float*)d_in[11];
    const float* bhh_w = (const float*)d_in[12];

    char* ws = (char*)d_ws;
    float*  in_gates = (float*)(ws + IN_GATES_OFF);
    float*  last     = (float*)(ws + LAST_OFF);
    float2* WT2c     = (float2*)(ws + WT2C_OFF);
    float2* WT2w     = (float2*)(ws + WT2W_OFF);
    unsigned long long* ring = (unsigned long long*)(ws + RING_OFF);
    unsigned int* flags      = (unsigned int*)(ws + FLAGS_OFF);

    hipLaunchKernelGGL(prep_c_kernel, dim3(1024), dim3(256), 0, stream,
                       Wih_c, Whh_c, WT2c);
    hipLaunchKernelGGL(prep_w_kernel, dim3(6144), dim3(256), 0, stream,
                       Wih_w, WT2w);
    hipLaunchKernelGGL(char_lstm_kernel, dim3(256), dim3(1024), 0, stream,
                       char_idxs, char_lens, char_emb, bih_c, bhh_c, WT2c, last);
    // ring mirrors + flags alias WT2c — zero only after char_lstm consumed the
    // weights. All mirrors' slot0 = {tag=0, h=0} (valid t=0 input); slots 1/2 +
    // flags start at 0.
    hipMemsetAsync(ws + RING_OFF, 0,
                   NMIR * RING_U64 * sizeof(unsigned long long) + 256 * sizeof(unsigned int),
                   stream);
    hipLaunchKernelGGL(fused_word_kernel, dim3(NWG_RNN + NWB_WIN), dim3(512), 0, stream,
                       Whh_w, word_idxs, word_emb, last, WT2w, bih_w, bhh_w,
                       in_gates, ring, flags, (float*)d_out);
}